// Round 8
// baseline (2201.767 us; speedup 1.0000x reference)
//
#include <hip/hip_runtime.h>
#include <hip/hip_cooperative_groups.h>
#include <cmath>

namespace cg = cooperative_groups;

// DTASNN embedding, fully fused: all T=5 recurrent steps in ONE cooperative kernel.
// Block (b, row-pair) owns the same 2x64 px x 64 co outputs every step -> vmem and
// the spike-count accumulator live in REGISTERS across steps; only spikes go
// through global (bf16 ping-pong), separated by grid.sync().
// bf16 triple-limb weights (w = hi+mid+lo): MFMA sequence identical to R7 ->
// bit-exact output (R6/R7 measured absmax 0.0).
//
// ws: evbf 20MB [b][tp][h][w][c] | sA 4MB | sB 4MB [b][h][w][c] | Wp 864KB | tabs

typedef __attribute__((ext_vector_type(8))) short short8;
typedef __attribute__((ext_vector_type(4))) float floatx4;

#define HW 64
#define TT 5
#define PLANE 4096
#define WP_ELEMS 147456            // per limb: 9 taps * 4 ks * 4 q * 128 o * 8 j
#define CDIM 136                   // 128 ch + 8 pad: odd-17 16B-quads -> conflict-free
#define UELEMS (4 * 66 * CDIM)     // 71808 B LDS

__device__ __forceinline__ ushort f2bf_rne(float f) {
  uint u = __float_as_uint(f);
  return (ushort)((u + 0x7FFFu + ((u >> 16) & 1u)) >> 16);
}
__device__ __forceinline__ float bf2f(ushort h) {
  return __uint_as_float(((uint)h) << 16);
}

// ---- prep 1: weights -> triple-limb MFMA A-frag layout (as R6/R7) ----
__global__ __launch_bounds__(256) void prep_weights(
    const float* __restrict__ w_in, const float* __restrict__ w_gate,
    ushort* __restrict__ Wp)
{
  int idx = blockIdx.x * 256 + threadIdx.x;
  if (idx >= WP_ELEMS) return;
  int j   = idx & 7;
  int o   = (idx >> 3) & 127;
  int q   = (idx >> 10) & 3;
  int ks  = (idx >> 12) & 3;
  int tap = idx >> 14;                       // 0..8 (kh*3+kw)
  int c   = ks * 32 + q * 8 + j;             // 0..127
  int g = o >> 4, i = o & 15;
  int row = (i >> 3) * 64 + (g * 8 + (i & 7));
  float w = (c < 64) ? w_in[(row * 64 + c) * 9 + tap]
                     : w_gate[(row * 64 + (c - 64)) * 9 + tap];
  ushort h = f2bf_rne(w);
  float r1 = w - bf2f(h);
  ushort m = f2bf_rne(r1);
  float r2 = r1 - bf2f(m);
  ushort l = f2bf_rne(r2);
  Wp[idx] = h;
  Wp[WP_ELEMS + idx] = m;
  Wp[2 * WP_ELEMS + idx] = l;
}

// ---- prep 2: events fp32 [b][tp][c][h][w] -> bf16 ch-minor [b][tp][h][w][c] ----
__global__ __launch_bounds__(256) void prep_events(
    const float* __restrict__ ev, ushort* __restrict__ evbf)
{
  const int row  = blockIdx.x * 4 + (threadIdx.x >> 6);  // 0..2559 = (b,tp,h)
  const int lane = threadIdx.x & 63;                     // = w
  const int b  = row / (TT * HW);
  const int rm = row % (TT * HW);
  const int tp = rm / HW;
  const int h  = rm % HW;
  const float* src = ev + ((size_t)(b * TT + tp) * 64) * PLANE + h * HW + lane;
  ushort* dst = evbf + ((size_t)((b * TT + tp) * PLANE + h * HW + lane)) * 64;
#pragma unroll
  for (int k = 0; k < 8; ++k) {
    short8 v;
#pragma unroll
    for (int j = 0; j < 8; ++j)
      v[j] = (src[(size_t)(k * 8 + j) * PLANE] != 0.f) ? (short)0x3F80 : (short)0;
    *(short8*)(dst + k * 8) = v;
  }
}

// ---- prep 3: tabs = bc[64] | bg[64] | th[5][64] ----
__global__ __launch_bounds__(512) void prep_tables(
    const float* __restrict__ b_in, const float* __restrict__ b_gate,
    const float* __restrict__ tdec, float* __restrict__ tabs)
{
  int i = threadIdx.x;
  if (i < 64)      tabs[i] = b_in[i] + b_gate[i];
  else if (i < 128) tabs[i] = b_in[i] + b_gate[i];           // i-64+64
  else if (i < 128 + TT * 64) {
    int t = (i - 128) >> 6, co = (i - 128) & 63;
    tabs[i] = powf(tdec[co], (float)t);                      // THRESH=1.0
  }
}

// ---- the fused SNN ----
__global__ __launch_bounds__(1024, 4) void snn_fused(
    const ushort* __restrict__ evbf,
    const ushort* __restrict__ Wp,
    const float*  __restrict__ tabs,
    ushort*       __restrict__ sA,      // spikes ping
    ushort*       __restrict__ sB,      // spikes pong
    float*        __restrict__ outp)
{
  cg::grid_group gg = cg::this_grid();
  __shared__ ushort U[UELEMS];   // [row4][col66][c136]: rows r0-1..r0+2, col=img+1

  const int tid = threadIdx.x;               // 0..1023
  const int b   = blockIdx.x >> 5;
  const int r0  = (blockIdx.x & 31) * 2;     // img rows r0, r0+1

  const int lane = tid & 63;
  const int g    = (tid >> 6) & 7;           // o-group 0..7
  const int hf   = tid >> 9;                 // tile-half 0/1 (img row r0+hf)
  const int ln   = lane & 15;                // = A's m = B's n (px col in tile)
  const int q    = lane >> 4;                // k-octet group 0..3

  // staging mapping: 4 rows x 64 cols x 4 ch-chunks = 1024 threads
  const int srow = tid >> 8;                 // lds row 0..3
  const int scol = (tid >> 2) & 63;          // img col
  const int sch  = tid & 3;                  // 16-ch chunk
  const int sr   = r0 + srow - 1;            // img row (may be out of range)
  const bool svalid = (sr >= 0) && (sr < HW);
  ushort* du = U + (srow * 66 + scol + 1) * CDIM;
  const size_t epx = ((size_t)(sr * HW + scol)) * 64 + sch * 16;   // within a plane
  const size_t spx = ((size_t)((b * HW + sr) * HW + scol)) * 64 + sch * 16;

  // zero LDS ONCE: halo rows/cols never written later, stay 0 = SAME padding
  for (int i = tid; i < UELEMS / 8; i += 1024) ((short8*)U)[i] = short8{0,0,0,0,0,0,0,0};

  // epilogue constants (q<2 lanes use them)
  float bc[4], bg[4];
#pragma unroll
  for (int r = 0; r < 4; ++r) {
    const int co = g * 8 + (q & 1) * 4 + r;
    bc[r] = tabs[co];
    bg[r] = tabs[64 + co];
  }
  const ushort* wpl = Wp + (size_t)q * 1024 + (g * 16 + ln) * 8;  // A-frag lane base
  const int laneB = ln * CDIM + q * 8;
  const int hh  = r0 + hf;

  float vm[4][4], ot[4][4];                  // vmem + spike-count, in REGISTERS
#pragma unroll
  for (int tt = 0; tt < 4; ++tt)
#pragma unroll
    for (int r = 0; r < 4; ++r) { vm[tt][r] = 0.f; ot[tt][r] = 0.f; }

  for (int t = 0; t < TT; ++t) {
    // ---- stage events + spikes (pure short8 copies; conflict-free quads) ----
    if (svalid) {
      const ushort* es = evbf + (size_t)(b * TT + (TT - 1 - t)) * PLANE * 64 + epx;
      const ushort* ss = ((t & 1) ? sB : sA) + spx;
      *(short8*)(du + sch * 16)          = *(const short8*)(es);
      *(short8*)(du + sch * 16 + 8)      = *(const short8*)(es + 8);
      *(short8*)(du + 64 + sch * 16)     = *(const short8*)(ss);
      *(short8*)(du + 64 + sch * 16 + 8) = *(const short8*)(ss + 8);
    }
    __syncthreads();

    // ---- MFMA: acc[tt] = 16 o' x 16 px, tile (hf*4+tt), K=128x9taps, 3 limbs ----
    floatx4 acc[4];
#pragma unroll
    for (int tt = 0; tt < 4; ++tt) acc[tt] = floatx4{0.f, 0.f, 0.f, 0.f};

    for (int tap = 0; tap < 9; ++tap) {
      const int kh = tap / 3, kw = tap % 3;
      short8 Ah[4], Am[4], Al[4];
      const ushort* wpt = wpl + tap * 16384;
#pragma unroll
      for (int ks = 0; ks < 4; ++ks) {
        Ah[ks] = *(const short8*)(wpt + ks * 4096);
        Am[ks] = *(const short8*)(wpt + WP_ELEMS + ks * 4096);
        Al[ks] = *(const short8*)(wpt + 2 * WP_ELEMS + ks * 4096);
      }
#pragma unroll
      for (int tt = 0; tt < 4; ++tt) {
        const int xbase = (hf + kh) * 66 * CDIM + (tt * 16 + kw) * CDIM;
#pragma unroll
        for (int ks = 0; ks < 4; ++ks) {
          short8 B = *(const short8*)(U + xbase + ks * 32 + laneB);
          acc[tt] = __builtin_amdgcn_mfma_f32_16x16x32_bf16(Ah[ks], B, acc[tt], 0, 0, 0);
          acc[tt] = __builtin_amdgcn_mfma_f32_16x16x32_bf16(Am[ks], B, acc[tt], 0, 0, 0);
          acc[tt] = __builtin_amdgcn_mfma_f32_16x16x32_bf16(Al[ks], B, acc[tt], 0, 0, 0);
        }
      }
    }

    // ---- LIF epilogue (regs). D: col=lane&15, row(o')=q*4+reg.
    // lane l (q<2: cur rows) <-> l^32 (gate rows, same co,px).
    ushort* sdst = (t & 1) ? sA : sB;
    float th[4];
#pragma unroll
    for (int r = 0; r < 4; ++r)
      th[r] = tabs[128 + t * 64 + (g * 8 + (q & 1) * 4 + r)];
#pragma unroll
    for (int tt = 0; tt < 4; ++tt) {
      const int col = tt * 16 + ln;
      uint pack[2];
#pragma unroll
      for (int r = 0; r < 4; ++r) {
        const float other = __shfl_xor(acc[tt][r], 32, 64);
        uint sv = 0;
        if (q < 2) {
          const float cur  = acc[tt][r] + bc[r];
          const float gp   = other + bg[r];
          const float gate = 1.f / (1.f + expf(-gp));
          const float v    = gate * vm[tt][r] + cur;   // vmem = gate*vmem + current
          const bool fired = (v >= th[r]);             // heaviside(v - thresh_t)
          vm[tt][r] = fired ? 0.f : v;                 // hard reset to VRESET=0
          ot[tt][r] += fired ? 1.f : 0.f;
          sv = fired ? 0x3F80u : 0u;
        }
        if (r & 1) pack[r >> 1] |= (sv << 16);
        else       pack[r >> 1]  = sv;
      }
      if (q < 2) {
        const size_t sidx = ((size_t)((b * HW + hh) * HW + col)) * 64 + g * 8 + q * 4;
        *(uint2*)(sdst + sidx) = uint2{pack[0], pack[1]};  // 4 contiguous co
      }
    }

    __threadfence();                         // release spike writes device-wide
    gg.sync();                               // all blocks done; also block barrier
    __threadfence();                         // acquire (invalidate L1 for spike reads)
  }

  // ---- final: mean over T=5 ----
  if (q < 2) {
#pragma unroll
    for (int tt = 0; tt < 4; ++tt) {
      const int col = tt * 16 + ln;
#pragma unroll
      for (int r = 0; r < 4; ++r) {
        const int co = g * 8 + q * 4 + r;
        outp[((size_t)((b * 64 + co) * HW + hh)) * HW + col] = ot[tt][r] * 0.2f;
      }
    }
  }
}

extern "C" void kernel_launch(void* const* d_in, const int* in_sizes, int n_in,
                              void* d_out, int out_size, void* d_ws, size_t ws_size,
                              hipStream_t stream) {
  const float* events = (const float*)d_in[0];
  const float* w_in   = (const float*)d_in[1];
  const float* b_in   = (const float*)d_in[2];
  const float* w_gate = (const float*)d_in[3];
  const float* b_gate = (const float*)d_in[4];
  const float* tdec   = (const float*)d_in[5];
  float* out = (float*)d_out;

  char* base = (char*)d_ws;
  ushort* evbf = (ushort*)base;                      // 20,971,520 B
  ushort* sA   = (ushort*)(base + 20971520);         //  4,194,304 B
  ushort* sB   = (ushort*)(base + 25165824);         //  4,194,304 B
  ushort* Wp   = (ushort*)(base + 29360128);         //    884,736 B
  float*  tabs = (float*) (base + 30244864);         //      1,792 B

  hipMemsetAsync(sA, 0, 4194304, stream);            // t=0 spikes = 0

  hipLaunchKernelGGL(prep_weights, dim3(576), dim3(256), 0, stream, w_in, w_gate, Wp);
  hipLaunchKernelGGL(prep_events,  dim3(640), dim3(256), 0, stream, events, evbf);
  hipLaunchKernelGGL(prep_tables,  dim3(1),   dim3(512), 0, stream, b_in, b_gate, tdec, tabs);

  void* kargs[] = {(void*)&evbf, (void*)&Wp, (void*)&tabs,
                   (void*)&sA, (void*)&sB, (void*)&out};
  hipLaunchCooperativeKernel((const void*)snn_fused, dim3(256), dim3(1024),
                             kargs, 0, stream);
}

// Round 10
// 1886.040 us; speedup vs baseline: 1.1674x; 1.1674x over previous
//
#include <hip/hip_runtime.h>
#include <hip/hip_cooperative_groups.h>
#include <cmath>

namespace cg = cooperative_groups;

// DTASNN embedding, fully fused: all T=5 recurrent steps in ONE cooperative kernel.
// Block (b, row-pair) owns the same 2x64 px x 64 co outputs every step.
// R10 = R9 with the final-readout OOB fixed (px index double-counted the row dim:
// LDS read up to 13051/8704 + outp col up to 127/63 -> HSA fault -> abort).
// R9 vs R8: vmem + spike-count in LDS not registers (R8 spilled: 1.9GB scratch).
// bf16 triple-limb weights (w = hi+mid+lo): MFMA sequence identical to R7/R8 ->
// bit-exact output (measured absmax 0.0 in R6/R7/R8).
//
// ws: evbf 20MB [b][tp][h][w][c] | sA 4MB | sB 4MB [b][h][w][c] | Wp 864KB | tabs

typedef __attribute__((ext_vector_type(8))) short short8;
typedef __attribute__((ext_vector_type(4))) float floatx4;

#define HW 64
#define TT 5
#define PLANE 4096
#define WP_ELEMS 147456            // per limb: 9 taps * 4 ks * 4 q * 128 o * 8 j
#define CDIM 136                   // 128 ch + 8 pad: odd-17 16B-quads -> conflict-free
#define UELEMS (4 * 66 * CDIM)     // 71808 B
#define VPAD 68                    // VM/CNT px stride (odd-17 quads)

__device__ __forceinline__ ushort f2bf_rne(float f) {
  uint u = __float_as_uint(f);
  return (ushort)((u + 0x7FFFu + ((u >> 16) & 1u)) >> 16);
}
__device__ __forceinline__ float bf2f(ushort h) {
  return __uint_as_float(((uint)h) << 16);
}

// ---- prep 1: weights -> triple-limb MFMA A-frag layout ----
__global__ __launch_bounds__(256) void prep_weights(
    const float* __restrict__ w_in, const float* __restrict__ w_gate,
    ushort* __restrict__ Wp)
{
  int idx = blockIdx.x * 256 + threadIdx.x;
  if (idx >= WP_ELEMS) return;
  int j   = idx & 7;
  int o   = (idx >> 3) & 127;
  int q   = (idx >> 10) & 3;
  int ks  = (idx >> 12) & 3;
  int tap = idx >> 14;                       // 0..8 (kh*3+kw)
  int c   = ks * 32 + q * 8 + j;             // 0..127
  int g = o >> 4, i = o & 15;
  int row = (i >> 3) * 64 + (g * 8 + (i & 7));
  float w = (c < 64) ? w_in[(row * 64 + c) * 9 + tap]
                     : w_gate[(row * 64 + (c - 64)) * 9 + tap];
  ushort h = f2bf_rne(w);
  float r1 = w - bf2f(h);
  ushort m = f2bf_rne(r1);
  float r2 = r1 - bf2f(m);
  ushort l = f2bf_rne(r2);
  Wp[idx] = h;
  Wp[WP_ELEMS + idx] = m;
  Wp[2 * WP_ELEMS + idx] = l;
}

// ---- prep 2: events fp32 [b][tp][c][h][w] -> bf16 ch-minor [b][tp][h][w][c] ----
__global__ __launch_bounds__(256) void prep_events(
    const float* __restrict__ ev, ushort* __restrict__ evbf)
{
  const int row  = blockIdx.x * 4 + (threadIdx.x >> 6);  // 0..2559 = (b,tp,h)
  const int lane = threadIdx.x & 63;                     // = w
  const int b  = row / (TT * HW);
  const int rm = row % (TT * HW);
  const int tp = rm / HW;
  const int h  = rm % HW;
  const float* src = ev + ((size_t)(b * TT + tp) * 64) * PLANE + h * HW + lane;
  ushort* dst = evbf + ((size_t)((b * TT + tp) * PLANE + h * HW + lane)) * 64;
#pragma unroll
  for (int k = 0; k < 8; ++k) {
    short8 v;
#pragma unroll
    for (int j = 0; j < 8; ++j)
      v[j] = (src[(size_t)(k * 8 + j) * PLANE] != 0.f) ? (short)0x3F80 : (short)0;
    *(short8*)(dst + k * 8) = v;
  }
}

// ---- prep 3: tabs = bc[64] | bg[64] | th[5][64] ----
__global__ __launch_bounds__(512) void prep_tables(
    const float* __restrict__ b_in, const float* __restrict__ b_gate,
    const float* __restrict__ tdec, float* __restrict__ tabs)
{
  int i = threadIdx.x;
  if (i < 128) tabs[i] = b_in[i] + b_gate[i];
  else if (i < 128 + TT * 64) {
    int t = (i - 128) >> 6, co = (i - 128) & 63;
    tabs[i] = powf(tdec[co], (float)t);                      // THRESH=1.0
  }
}

// ---- the fused SNN ----
__global__ __launch_bounds__(1024, 4) void snn_fused(
    const ushort* __restrict__ evbf,
    const ushort* __restrict__ Wp,
    const float*  __restrict__ tabs,
    ushort*       __restrict__ sA,      // spikes ping
    ushort*       __restrict__ sB,      // spikes pong
    float*        __restrict__ outp)
{
  cg::grid_group gg = cg::this_grid();
  __shared__ ushort U[UELEMS];              // input tile  [row4][col66][c136]
  __shared__ float  VM[128 * VPAD];         // vmem        [px][co(+pad)]
  __shared__ unsigned char CNT[128 * VPAD]; // spike count [px][co(+pad)]

  const int tid = threadIdx.x;               // 0..1023
  const int b   = blockIdx.x >> 5;
  const int r0  = (blockIdx.x & 31) * 2;     // img rows r0, r0+1

  const int lane = tid & 63;
  const int g    = (tid >> 6) & 7;           // o-group 0..7
  const int hf   = tid >> 9;                 // tile-half 0/1 (img row r0+hf)
  const int ln   = lane & 15;                // = A's m = B's n (px col in tile)
  const int q    = lane >> 4;                // k-octet group 0..3

  // staging mapping: 4 rows x 64 cols x 4 ch-chunks = 1024 threads
  const int srow = tid >> 8;                 // lds row 0..3
  const int scol = (tid >> 2) & 63;          // img col
  const int sch  = tid & 3;                  // 16-ch chunk
  const int sr   = r0 + srow - 1;            // img row (may be out of range)
  const bool svalid = (sr >= 0) && (sr < HW);
  ushort* du = U + (srow * 66 + scol + 1) * CDIM;
  const size_t epx = ((size_t)(sr * HW + scol)) * 64 + sch * 16;   // within a plane
  const size_t spx = ((size_t)((b * HW + sr) * HW + scol)) * 64 + sch * 16;

  // ---- zero LDS state (halo rows/cols of U never written later = SAME pad) ----
  for (int i = tid; i < UELEMS / 8; i += 1024) ((short8*)U)[i] = short8{0,0,0,0,0,0,0,0};
  for (int i = tid; i < 128 * VPAD; i += 1024) VM[i] = 0.f;
  for (int i = tid; i < 128 * VPAD / 4; i += 1024) ((uint*)CNT)[i] = 0u;
  __syncthreads();                           // zero-init complete before staging

  // epilogue constants (q<2 lanes use them; (q&1)==q there)
  float bc[4], bg[4];
#pragma unroll
  for (int r = 0; r < 4; ++r) {
    const int co = g * 8 + (q & 1) * 4 + r;
    bc[r] = tabs[co];
    bg[r] = tabs[64 + co];
  }
  const ushort* wpl = Wp + (size_t)q * 1024 + (g * 16 + ln) * 8;  // A-frag lane base
  const int laneB = ln * CDIM + q * 8;
  const int hh  = r0 + hf;
  const int co0 = g * 8 + (q & 1) * 4;
  const size_t sidx_base = ((size_t)(b * HW + hh) * HW) * 64 + co0;

  for (int t = 0; t < TT; ++t) {
    // ---- stage events + spikes (pure short8 copies; conflict-free quads) ----
    if (svalid) {
      const ushort* es = evbf + (size_t)(b * TT + (TT - 1 - t)) * PLANE * 64 + epx;
      const ushort* ss = ((t & 1) ? sB : sA) + spx;
      *(short8*)(du + sch * 16)          = *(const short8*)(es);
      *(short8*)(du + sch * 16 + 8)      = *(const short8*)(es + 8);
      *(short8*)(du + 64 + sch * 16)     = *(const short8*)(ss);
      *(short8*)(du + 64 + sch * 16 + 8) = *(const short8*)(ss + 8);
    }
    __syncthreads();

    // ---- MFMA: acc[tt] = 16 o' x 16 px, tile (hf*4+tt), K=128x9taps, 3 limbs ----
    floatx4 acc[4];
#pragma unroll
    for (int tt = 0; tt < 4; ++tt) acc[tt] = floatx4{0.f, 0.f, 0.f, 0.f};

    for (int tap = 0; tap < 9; ++tap) {
      const int kh = tap / 3, kw = tap % 3;
      short8 Ah[4], Am[4], Al[4];
      const ushort* wpt = wpl + tap * 16384;
#pragma unroll
      for (int ks = 0; ks < 4; ++ks) {
        Ah[ks] = *(const short8*)(wpt + ks * 4096);
        Am[ks] = *(const short8*)(wpt + WP_ELEMS + ks * 4096);
        Al[ks] = *(const short8*)(wpt + 2 * WP_ELEMS + ks * 4096);
      }
#pragma unroll
      for (int tt = 0; tt < 4; ++tt) {
        const int xbase = (hf + kh) * 66 * CDIM + (tt * 16 + kw) * CDIM;
#pragma unroll
        for (int ks = 0; ks < 4; ++ks) {
          short8 B = *(const short8*)(U + xbase + ks * 32 + laneB);
          acc[tt] = __builtin_amdgcn_mfma_f32_16x16x32_bf16(Ah[ks], B, acc[tt], 0, 0, 0);
          acc[tt] = __builtin_amdgcn_mfma_f32_16x16x32_bf16(Am[ks], B, acc[tt], 0, 0, 0);
          acc[tt] = __builtin_amdgcn_mfma_f32_16x16x32_bf16(Al[ks], B, acc[tt], 0, 0, 0);
        }
      }
    }

    // ---- LIF epilogue: state in LDS (lane-private slots -> race-free).
    // D: col=lane&15, row(o')=q*4+reg; lane l (q<2: cur) <-> l^32 (gate).
    ushort* sdst = (t & 1) ? sA : sB;
    float th[4];
#pragma unroll
    for (int r = 0; r < 4; ++r)
      th[r] = tabs[128 + t * 64 + (co0 + r)];
#pragma unroll
    for (int tt = 0; tt < 4; ++tt) {
      const int col = tt * 16 + ln;
      const int px  = hf * 64 + col;
      float other[4];
#pragma unroll
      for (int r = 0; r < 4; ++r) other[r] = __shfl_xor(acc[tt][r], 32, 64);
      if (q < 2) {
        float4 vm4 = *(float4*)&VM[px * VPAD + co0];
        uint pack[2]; uint fm = 0;
#pragma unroll
        for (int r = 0; r < 4; ++r) {
          const float cur  = acc[tt][r] + bc[r];
          const float gp   = other[r] + bg[r];
          const float gate = 1.f / (1.f + expf(-gp));
          const float v    = gate * (&vm4.x)[r] + cur;  // vmem = gate*vmem + current
          const bool fired = (v >= th[r]);              // heaviside(v - thresh_t)
          (&vm4.x)[r] = fired ? 0.f : v;                // hard reset to VRESET=0
          fm |= fired ? (1u << (8 * r)) : 0u;
          const uint sv = fired ? 0x3F80u : 0u;
          if (r & 1) pack[r >> 1] |= (sv << 16);
          else       pack[r >> 1]  = sv;
        }
        *(float4*)&VM[px * VPAD + co0] = vm4;
        *(uint*)&CNT[px * VPAD + co0] += fm;            // u8 counters, exact (<=5)
        *(uint2*)(sdst + sidx_base + (size_t)col * 64) = uint2{pack[0], pack[1]};
      }
    }

    if (t + 1 < TT) {                        // cross-block spike handoff
      __threadfence();                       // release spike writes device-wide
      gg.sync();
      __threadfence();                       // acquire before next staging reads
    }
  }

  // ---- final: out[b][co][h][w] = count * 0.2 (exact: n in 0..5 -> n*0.2) ----
  // 1024 threads = 64 co x 16 groups x 8 px; px in 0..127 encodes (row,col).
  __syncthreads();                           // CNT writes visible to remapped threads
  {
    const int co = tid >> 4;                 // 0..63
    const int p8 = (tid & 15) * 8;           // px base 0..120 (8 px, same row)
    const int row = p8 >> 6;                 // 0/1
    const int col = p8 & 63;                 // multiple of 8
    float o[8];
#pragma unroll
    for (int j = 0; j < 8; ++j)
      o[j] = (float)CNT[(p8 + j) * VPAD + co] * 0.2f;
    float4* dst = (float4*)&outp[((size_t)(b * 64 + co) * HW + (r0 + row)) * HW + col];
    dst[0] = float4{o[0], o[1], o[2], o[3]};
    dst[1] = float4{o[4], o[5], o[6], o[7]};
  }
}

extern "C" void kernel_launch(void* const* d_in, const int* in_sizes, int n_in,
                              void* d_out, int out_size, void* d_ws, size_t ws_size,
                              hipStream_t stream) {
  const float* events = (const float*)d_in[0];
  const float* w_in   = (const float*)d_in[1];
  const float* b_in   = (const float*)d_in[2];
  const float* w_gate = (const float*)d_in[3];
  const float* b_gate = (const float*)d_in[4];
  const float* tdec   = (const float*)d_in[5];
  float* out = (float*)d_out;

  char* base = (char*)d_ws;
  ushort* evbf = (ushort*)base;                      // 20,971,520 B
  ushort* sA   = (ushort*)(base + 20971520);         //  4,194,304 B
  ushort* sB   = (ushort*)(base + 25165824);         //  4,194,304 B
  ushort* Wp   = (ushort*)(base + 29360128);         //    884,736 B
  float*  tabs = (float*) (base + 30244864);         //      1,792 B

  hipMemsetAsync(sA, 0, 4194304, stream);            // t=0 spikes = 0

  hipLaunchKernelGGL(prep_weights, dim3(576), dim3(256), 0, stream, w_in, w_gate, Wp);
  hipLaunchKernelGGL(prep_events,  dim3(640), dim3(256), 0, stream, events, evbf);
  hipLaunchKernelGGL(prep_tables,  dim3(1),   dim3(512), 0, stream, b_in, b_gate, tdec, tabs);

  void* kargs[] = {(void*)&evbf, (void*)&Wp, (void*)&tabs,
                   (void*)&sA, (void*)&sB, (void*)&out};
  hipLaunchCooperativeKernel((const void*)snn_fused, dim3(256), dim3(1024),
                             kargs, 0, stream);
}

// Round 12
// 247.319 us; speedup vs baseline: 8.9026x; 7.6259x over previous
//
#include <hip/hip_runtime.h>
#include <cmath>

// DTASNN embedding via i8 QUAD-limb MFMA implicit conv (5-launch, no cooperative).
//
// Inputs binary {0,1} -> exact in i8. Weights as 4 signed-i8 fixed-point limbs:
//   w = 2^-8*L1 + 2^-15*L2 + 2^-22*L3 + 2^-29*L4 + eps, |eps| <= 2^-30
// mfma_i32_16x16x64_i8 accumulates EXACT integers; summed residual RMS ~1e-8.
// R11 (3 limbs, residual 2^-23/weight -> ~1.3e-6 summed) flipped exactly ONE
// spike decision (absmax 0.2012); 4th limb buys 100x margin below that.
//
// vs R7 (bf16 3-limb, 286us passing): 288 vs 432 MFMA/wave, half the B LDS
// traffic, 2/3 A-frag bytes. R8/R10: coop-fusion fences thrash L2 -> abandoned.
//
// ws: vmem fp32 8MB | sA i8 2MB | sB i8 2MB | evb i8 10.5MB | Wp 576KB | tabs

typedef __attribute__((ext_vector_type(4))) int intx4;

#define HW 64
#define TT 5
#define PLANE 4096
#define CSTR 144                  // U px stride bytes (128 ch + 16 pad): odd 9 quads
#define USIZE (4 * 66 * CSTR)     // 38016 B
#define WPL 147456                // per-limb Wp bytes: 9 tap * 2 ks * 4 q * 128 o * 16

// ---- prep: weight limbs (+ bias/threshold tables) ----
// Wp[limb] layout: addr = ((tap*2+ks)*4 + q)*2048 + o*16 + j ; o = g*16+i,
// i<8 -> cur row co=g*8+i, i>=8 -> gate row 64+co; c = ks*64 + q*16 + j.
__global__ __launch_bounds__(256) void prep_w(
    const float* __restrict__ w_in, const float* __restrict__ w_gate,
    const float* __restrict__ b_in, const float* __restrict__ b_gate,
    const float* __restrict__ tdec,
    signed char* __restrict__ Wp, float* __restrict__ tabs)
{
  const int idx = blockIdx.x * 256 + threadIdx.x;
  if (idx < 9216) {
    const int o   = idx & 127;
    const int q   = (idx >> 7) & 3;
    const int ks  = (idx >> 9) & 1;
    const int tap = idx >> 10;               // 0..8
    const int g = o >> 4, i = o & 15;
    const int row = (i >> 3) * 64 + g * 8 + (i & 7);
    int p1[4], p2[4], p3[4], p4[4];
#pragma unroll
    for (int wd = 0; wd < 4; ++wd) {
      int v1 = 0, v2 = 0, v3 = 0, v4 = 0;
#pragma unroll
      for (int jb = 0; jb < 4; ++jb) {
        const int j = wd * 4 + jb;
        const int c = ks * 64 + q * 16 + j;
        const float w = (c < 64) ? w_in[(row * 64 + c) * 9 + tap]
                                 : w_gate[(row * 64 + (c - 64)) * 9 + tap];
        float a1 = fminf(fmaxf(rintf(w * 256.f), -127.f), 127.f);
        float r1 = w * 256.f - a1;              // in [-0.5, 0.5]
        float a2 = rintf(r1 * 128.f);           // |a2| <= 64
        float r2 = r1 * 128.f - a2;
        float a3 = rintf(r2 * 128.f);
        float r3 = r2 * 128.f - a3;
        float a4 = rintf(r3 * 128.f);
        v1 |= ((int)a1 & 255) << (8 * jb);
        v2 |= ((int)a2 & 255) << (8 * jb);
        v3 |= ((int)a3 & 255) << (8 * jb);
        v4 |= ((int)a4 & 255) << (8 * jb);
      }
      p1[wd] = v1; p2[wd] = v2; p3[wd] = v3; p4[wd] = v4;
    }
    intx4* d = (intx4*)(Wp + (size_t)idx * 16);
    d[0]                          = intx4{p1[0], p1[1], p1[2], p1[3]};
    *(intx4*)((char*)d + WPL)     = intx4{p2[0], p2[1], p2[2], p2[3]};
    *(intx4*)((char*)d + 2 * WPL) = intx4{p3[0], p3[1], p3[2], p3[3]};
    *(intx4*)((char*)d + 3 * WPL) = intx4{p4[0], p4[1], p4[2], p4[3]};
  }
  if (idx < 448) {                           // tabs: bc|bg [128], th [5][64]
    if (idx < 128) tabs[idx] = b_in[idx] + b_gate[idx];
    else {
      const int t = (idx - 128) >> 6, co = (idx - 128) & 63;
      tabs[idx] = powf(tdec[co], (float)t);  // THRESH=1.0
    }
  }
}

// ---- prep: events fp32 [b][tp][c][h][w] -> i8 ch-minor [b][tp][h][w][c] ----
__global__ __launch_bounds__(256) void prep_ev(
    const float* __restrict__ ev, signed char* __restrict__ evb)
{
  const int row  = blockIdx.x * 4 + (threadIdx.x >> 6);  // 0..2559 = (b,tp,h)
  const int w    = threadIdx.x & 63;
  const int b  = row / (TT * HW);
  const int rm = row % (TT * HW);
  const int tp = rm / HW;
  const int h  = rm % HW;
  const float* src = ev + ((size_t)(b * TT + tp) * 64) * PLANE + h * HW + w;
  signed char* dst = evb + ((size_t)((b * TT + tp) * PLANE + h * HW + w)) * 64;
#pragma unroll
  for (int k = 0; k < 8; ++k) {
    unsigned long long pk = 0;
#pragma unroll
    for (int j = 0; j < 8; ++j)
      pk |= (src[(size_t)(k * 8 + j) * PLANE] != 0.f)
              ? (1ull << (8 * j)) : 0ull;
    *(unsigned long long*)(dst + k * 8) = pk;
  }
}

// ---- per-step kernel ----
__global__ __launch_bounds__(1024, 4) void snn_step(
    const signed char* __restrict__ evb,
    const signed char* __restrict__ Wp,
    const float*       __restrict__ tabs,
    float*             __restrict__ vmem,    // [b][co][h][w] fp32
    const signed char* __restrict__ s_src,   // [b][h][w][c] i8 {0,1}
    signed char*       __restrict__ s_dst,
    float*             __restrict__ outp,    // [b][co][h][w] fp32
    int t)
{
  __shared__ signed char U[USIZE];  // [row4][col66][c144]: rows r0-1..r0+2, col=img+1

  const int tid = threadIdx.x;               // 0..1023
  const int b   = blockIdx.x >> 5;
  const int r0  = (blockIdx.x & 31) * 2;     // img rows r0, r0+1

  const int lane = tid & 63;
  const int g    = (tid >> 6) & 7;           // o-group 0..7
  const int hf   = tid >> 9;                 // tile-half 0/1 (img row r0+hf)
  const int ln   = lane & 15;                // = A's m = B's n (px col in tile)
  const int q    = lane >> 4;                // k-group 0..3

  // ---- zero U (halo col 0/65, out-of-range rows stay 0 = SAME padding) ----
  for (int i = tid; i < USIZE / 16; i += 1024) ((intx4*)U)[i] = intx4{0, 0, 0, 0};

  // staging: 4 rows x 64 cols x 4 x 32B-chunks (ch 0-63 events, 64-127 spikes)
  const int srow = tid >> 8;
  const int scol = (tid >> 2) & 63;
  const int sch  = tid & 3;
  const int sr   = r0 + srow - 1;
  const bool svalid = (sr >= 0) && (sr < HW);
  signed char* du = U + (srow * 66 + scol + 1) * CSTR + sch * 32;
  const signed char* gsrc = nullptr;
  if (svalid) {
    gsrc = (sch < 2)
      ? evb + ((size_t)(b * TT + (TT - 1 - t)) * PLANE + sr * HW + scol) * 64 + sch * 32
      : s_src + ((size_t)((b * HW + sr) * HW + scol)) * 64 + (sch - 2) * 32;
  }
  __syncthreads();                           // zeroing done
  if (svalid) {
    *(intx4*)(du)      = *(const intx4*)(gsrc);
    *(intx4*)(du + 16) = *(const intx4*)(gsrc + 16);
  }
  __syncthreads();

  // ---- MFMA: acc[limb][tt] (i32, exact), tile (hf*4+tt), K=128 = 2 ks x 64 ----
  intx4 acc1[4], acc2[4], acc3[4], acc4[4];
#pragma unroll
  for (int tt = 0; tt < 4; ++tt) {
    acc1[tt] = intx4{0,0,0,0}; acc2[tt] = intx4{0,0,0,0};
    acc3[tt] = intx4{0,0,0,0}; acc4[tt] = intx4{0,0,0,0};
  }

  const int laneB = ln * CSTR + q * 16;
  const signed char* wlane = Wp + q * 2048 + (g * 16 + ln) * 16;

  for (int tap = 0; tap < 9; ++tap) {
    const int kh = (tap * 11) >> 5;          // tap/3
    const int kw = tap - 3 * kh;
#pragma unroll
    for (int ks = 0; ks < 2; ++ks) {
      const signed char* wp = wlane + (tap * 2 + ks) * 8192;
      const intx4 A1 = *(const intx4*)(wp);
      const intx4 A2 = *(const intx4*)(wp + WPL);
      const intx4 A3 = *(const intx4*)(wp + 2 * WPL);
      const intx4 A4 = *(const intx4*)(wp + 3 * WPL);
      const signed char* ub = U + (hf + kh) * (66 * CSTR) + kw * CSTR + ks * 64 + laneB;
#pragma unroll
      for (int tt = 0; tt < 4; ++tt) {
        const intx4 B = *(const intx4*)(ub + tt * (16 * CSTR));
        acc1[tt] = __builtin_amdgcn_mfma_i32_16x16x64_i8(A1, B, acc1[tt], 0, 0, 0);
        acc2[tt] = __builtin_amdgcn_mfma_i32_16x16x64_i8(A2, B, acc2[tt], 0, 0, 0);
        acc3[tt] = __builtin_amdgcn_mfma_i32_16x16x64_i8(A3, B, acc3[tt], 0, 0, 0);
        acc4[tt] = __builtin_amdgcn_mfma_i32_16x16x64_i8(A4, B, acc4[tt], 0, 0, 0);
      }
    }
  }

  // ---- LIF epilogue (same as verified R7). D: col=lane&15, row(o')=q*4+reg.
  // lane l (q<2: cur rows) <-> l^32 (gate rows, same co,px).
  const bool t0 = (t == 0), tL = (t == TT - 1);
  const int co0 = g * 8 + (q & 1) * 4;
  float bc[4], bg[4], th[4];
#pragma unroll
  for (int r = 0; r < 4; ++r) {
    bc[r] = tabs[co0 + r];
    bg[r] = tabs[64 + co0 + r];
    th[r] = tabs[128 + t * 64 + co0 + r];
  }
  const int hh = r0 + hf;
#pragma unroll
  for (int tt = 0; tt < 4; ++tt) {
    const int col = tt * 16 + ln;
    uint fm = 0;
#pragma unroll
    for (int r = 0; r < 4; ++r) {
      // exact-int -> fp32 reconstruction (power-of-2 scales; products exact;
      // small-to-large fmaf chain)
      const float mine = fmaf((float)acc1[tt][r], 0x1p-8f,
                         fmaf((float)acc2[tt][r], 0x1p-15f,
                         fmaf((float)acc3[tt][r], 0x1p-22f,
                              (float)acc4[tt][r] * 0x1p-29f)));
      const float other = __shfl_xor(mine, 32, 64);
      if (q < 2) {
        const int co = co0 + r;
        const size_t idx = ((size_t)((b * 64 + co) * HW + hh)) * HW + col;
        const float cur  = mine + bc[r];
        const float gp   = other + bg[r];
        const float gate = 1.f / (1.f + expf(-gp));
        const float v    = gate * vmem[idx] + cur;    // vmem = gate*vmem + current
        const bool fired = (v >= th[r]);              // heaviside(v - thresh_t)
        vmem[idx] = fired ? 0.f : v;                  // hard reset to VRESET=0
        fm |= fired ? (1u << (8 * r)) : 0u;
        float o = (t0 ? 0.f : outp[idx]) + (fired ? 1.f : 0.f);
        if (tL) o *= 0.2f;                            // mean over T=5
        outp[idx] = o;
      }
    }
    if (q < 2)                                        // 4 consecutive co, i8 {0,1}
      *(uint*)(s_dst + ((size_t)((b * HW + hh) * HW + col)) * 64 + co0) = fm;
  }
}

extern "C" void kernel_launch(void* const* d_in, const int* in_sizes, int n_in,
                              void* d_out, int out_size, void* d_ws, size_t ws_size,
                              hipStream_t stream) {
  const float* events = (const float*)d_in[0];
  const float* w_in   = (const float*)d_in[1];
  const float* b_in   = (const float*)d_in[2];
  const float* w_gate = (const float*)d_in[3];
  const float* b_gate = (const float*)d_in[4];
  const float* tdec   = (const float*)d_in[5];
  float* out = (float*)d_out;

  char* base = (char*)d_ws;
  float*       vmem = (float*)base;                    //  8,388,608 B
  signed char* sA   = (signed char*)(base + 8388608);  //  2,097,152 B
  signed char* sB   = (signed char*)(base + 10485760); //  2,097,152 B
  signed char* evb  = (signed char*)(base + 12582912); // 10,485,760 B
  signed char* Wp   = (signed char*)(base + 23068672); //    589,824 B (4 limbs)
  float*       tabs = (float*)(base + 23658496);       //      1,792 B

  hipMemsetAsync(base, 0, 10485760, stream);           // vmem + sA = 0

  hipLaunchKernelGGL(prep_w,  dim3(36),  dim3(256), 0, stream,
                     w_in, w_gate, b_in, b_gate, tdec, Wp, tabs);
  hipLaunchKernelGGL(prep_ev, dim3(640), dim3(256), 0, stream, events, evb);

  for (int t = 0; t < TT; ++t) {
    const signed char* ssrc = (t & 1) ? sB : sA;
    signed char*       sdst = (t & 1) ? sA : sB;
    hipLaunchKernelGGL(snn_step, dim3(256), dim3(1024), 0, stream,
                       evb, Wp, tabs, vmem, ssrc, sdst, out, t);
  }
}

// Round 13
// 236.482 us; speedup vs baseline: 9.3105x; 1.0458x over previous
//
#include <hip/hip_runtime.h>
#include <cmath>

// DTASNN embedding via i8 QUAD-limb MFMA implicit conv (5-launch + 1 tiny prep).
//
// Inputs binary {0,1} -> exact in i8. Weights as 4 signed-i8 fixed-point limbs:
//   w = 2^-8*L1 + 2^-15*L2 + 2^-22*L3 + 2^-29*L4 + eps, |eps| <= 2^-30
// mfma_i32_16x16x64_i8 accumulates EXACT integers; summed residual RMS ~1e-8
// (R11's 3-limb 1.3e-6 flipped exactly one spike; R12's 4-limb passed absmax 0.0).
//
// R13 vs R12 (whose graph head lost ~100us: memset node + prep_ev + dispatch
// boundaries before step 0 ran):
//  - prep_ev DELETED: fp32->i8 event conversion folded into snn_step staging
//    (16 lane-coalesced scalar loads + pack per thread; same (x!=0) predicate ->
//    staged bytes identical -> MFMA bit-exact).
//  - memset DELETED: t=0 reads no state (spike chunks skipped, U pre-zeroed;
//    vprev=0 instead of vmem read; outp write-only at t0). Poison never read.
//  - graph: 9 -> 6 dispatches.
//
// ws: vmem fp32 8MB | sA i8 2MB | sB i8 2MB | Wp 576KB | tabs

typedef __attribute__((ext_vector_type(4))) int intx4;

#define HW 64
#define TT 5
#define PLANE 4096
#define CSTR 144                  // U px stride bytes (128 ch + 16 pad): odd 9 quads
#define USIZE (4 * 66 * CSTR)     // 38016 B
#define WPL 147456                // per-limb Wp bytes: 9 tap * 2 ks * 4 q * 128 o * 16

// ---- prep: weight limbs + bias/threshold tables ----
// Wp[limb] layout: addr = ((tap*2+ks)*4 + q)*2048 + o*16 + j ; o = g*16+i,
// i<8 -> cur row co=g*8+i, i>=8 -> gate row 64+co; c = ks*64 + q*16 + j.
__global__ __launch_bounds__(256) void prep_w(
    const float* __restrict__ w_in, const float* __restrict__ w_gate,
    const float* __restrict__ b_in, const float* __restrict__ b_gate,
    const float* __restrict__ tdec,
    signed char* __restrict__ Wp, float* __restrict__ tabs)
{
  const int idx = blockIdx.x * 256 + threadIdx.x;
  if (idx < 9216) {
    const int o   = idx & 127;
    const int q   = (idx >> 7) & 3;
    const int ks  = (idx >> 9) & 1;
    const int tap = idx >> 10;               // 0..8
    const int g = o >> 4, i = o & 15;
    const int row = (i >> 3) * 64 + g * 8 + (i & 7);
    int p1[4], p2[4], p3[4], p4[4];
#pragma unroll
    for (int wd = 0; wd < 4; ++wd) {
      int v1 = 0, v2 = 0, v3 = 0, v4 = 0;
#pragma unroll
      for (int jb = 0; jb < 4; ++jb) {
        const int j = wd * 4 + jb;
        const int c = ks * 64 + q * 16 + j;
        const float w = (c < 64) ? w_in[(row * 64 + c) * 9 + tap]
                                 : w_gate[(row * 64 + (c - 64)) * 9 + tap];
        float a1 = fminf(fmaxf(rintf(w * 256.f), -127.f), 127.f);
        float r1 = w * 256.f - a1;              // in [-0.5, 0.5]
        float a2 = rintf(r1 * 128.f);           // |a2| <= 64
        float r2 = r1 * 128.f - a2;
        float a3 = rintf(r2 * 128.f);
        float r3 = r2 * 128.f - a3;
        float a4 = rintf(r3 * 128.f);
        v1 |= ((int)a1 & 255) << (8 * jb);
        v2 |= ((int)a2 & 255) << (8 * jb);
        v3 |= ((int)a3 & 255) << (8 * jb);
        v4 |= ((int)a4 & 255) << (8 * jb);
      }
      p1[wd] = v1; p2[wd] = v2; p3[wd] = v3; p4[wd] = v4;
    }
    intx4* d = (intx4*)(Wp + (size_t)idx * 16);
    d[0]                          = intx4{p1[0], p1[1], p1[2], p1[3]};
    *(intx4*)((char*)d + WPL)     = intx4{p2[0], p2[1], p2[2], p2[3]};
    *(intx4*)((char*)d + 2 * WPL) = intx4{p3[0], p3[1], p3[2], p3[3]};
    *(intx4*)((char*)d + 3 * WPL) = intx4{p4[0], p4[1], p4[2], p4[3]};
  }
  if (idx < 448) {                           // tabs: bc|bg [128], th [5][64]
    if (idx < 128) tabs[idx] = b_in[idx] + b_gate[idx];
    else {
      const int t = (idx - 128) >> 6, co = (idx - 128) & 63;
      tabs[idx] = powf(tdec[co], (float)t);  // THRESH=1.0
    }
  }
}

// ---- per-step kernel ----
__global__ __launch_bounds__(1024, 4) void snn_step(
    const float*       __restrict__ events,  // ORIGINAL fp32 [b][tp][c][h][w]
    const signed char* __restrict__ Wp,
    const float*       __restrict__ tabs,
    float*             __restrict__ vmem,    // [b][co][h][w] fp32
    const signed char* __restrict__ s_src,   // [b][h][w][c] i8 {0,1}
    signed char*       __restrict__ s_dst,
    float*             __restrict__ outp,    // [b][co][h][w] fp32
    int t)
{
  __shared__ signed char U[USIZE];  // [row4][col66][c144]: rows r0-1..r0+2, col=img+1

  const int tid = threadIdx.x;               // 0..1023
  const int b   = blockIdx.x >> 5;
  const int r0  = (blockIdx.x & 31) * 2;     // img rows r0, r0+1

  const int lane = tid & 63;
  const int g    = (tid >> 6) & 7;           // o-group 0..7
  const int hf   = tid >> 9;                 // tile-half 0/1 (img row r0+hf)
  const int ln   = lane & 15;                // = A's m = B's n (px col in tile)
  const int q    = lane >> 4;                // k-group 0..3

  // staging map: 4 rows x 64 cols x 4 ch-chunks(16) = 1024 threads
  const int srow = tid >> 8;
  const int scol = (tid >> 2) & 63;
  const int sch  = tid & 3;
  const int sr   = r0 + srow - 1;
  const bool svalid = (sr >= 0) && (sr < HW);

  // issue global loads BEFORE the zero-barrier (results land in regs)
  float ef[16];                              // event fp32 values, ch sch*16..+15
  intx4 sv = intx4{0, 0, 0, 0};              // spike bytes, ch 64+sch*16..+15
  if (svalid) {
    const float* es = events
        + ((size_t)((b * TT + (TT - 1 - t)) * 64 + sch * 16)) * PLANE
        + sr * HW + scol;
#pragma unroll
    for (int j = 0; j < 16; ++j) ef[j] = es[(size_t)j * PLANE];
    if (t > 0)                               // t=0: spikes are all-zero, skip read
      sv = *(const intx4*)(s_src + ((size_t)((b * HW + sr) * HW + scol)) * 64
                           + sch * 16);
  }

  // ---- zero U (halo col 0/65, out-of-range rows stay 0 = SAME padding) ----
  for (int i = tid; i < USIZE / 16; i += 1024) ((intx4*)U)[i] = intx4{0, 0, 0, 0};
  __syncthreads();                           // zeroing done

  if (svalid) {
    uint dw[4] = {0u, 0u, 0u, 0u};
#pragma unroll
    for (int j = 0; j < 16; ++j)             // same predicate as old prep_ev
      dw[j >> 2] |= (ef[j] != 0.f ? 1u : 0u) << (8 * (j & 3));
    signed char* du = U + (srow * 66 + scol + 1) * CSTR + sch * 16;
    *(intx4*)du        = intx4{(int)dw[0], (int)dw[1], (int)dw[2], (int)dw[3]};
    *(intx4*)(du + 64) = sv;                 // spike half (zeros at t=0)
  }
  __syncthreads();

  // ---- MFMA: acc[limb][tt] (i32, exact), tile (hf*4+tt), K=128 = 2 ks x 64 ----
  intx4 acc1[4], acc2[4], acc3[4], acc4[4];
#pragma unroll
  for (int tt = 0; tt < 4; ++tt) {
    acc1[tt] = intx4{0,0,0,0}; acc2[tt] = intx4{0,0,0,0};
    acc3[tt] = intx4{0,0,0,0}; acc4[tt] = intx4{0,0,0,0};
  }

  const int laneB = ln * CSTR + q * 16;
  const signed char* wlane = Wp + q * 2048 + (g * 16 + ln) * 16;

  for (int tap = 0; tap < 9; ++tap) {
    const int kh = (tap * 11) >> 5;          // tap/3
    const int kw = tap - 3 * kh;
#pragma unroll
    for (int ks = 0; ks < 2; ++ks) {
      const signed char* wp = wlane + (tap * 2 + ks) * 8192;
      const intx4 A1 = *(const intx4*)(wp);
      const intx4 A2 = *(const intx4*)(wp + WPL);
      const intx4 A3 = *(const intx4*)(wp + 2 * WPL);
      const intx4 A4 = *(const intx4*)(wp + 3 * WPL);
      const signed char* ub = U + (hf + kh) * (66 * CSTR) + kw * CSTR + ks * 64 + laneB;
#pragma unroll
      for (int tt = 0; tt < 4; ++tt) {
        const intx4 B = *(const intx4*)(ub + tt * (16 * CSTR));
        acc1[tt] = __builtin_amdgcn_mfma_i32_16x16x64_i8(A1, B, acc1[tt], 0, 0, 0);
        acc2[tt] = __builtin_amdgcn_mfma_i32_16x16x64_i8(A2, B, acc2[tt], 0, 0, 0);
        acc3[tt] = __builtin_amdgcn_mfma_i32_16x16x64_i8(A3, B, acc3[tt], 0, 0, 0);
        acc4[tt] = __builtin_amdgcn_mfma_i32_16x16x64_i8(A4, B, acc4[tt], 0, 0, 0);
      }
    }
  }

  // ---- LIF epilogue. D: col=lane&15, row(o')=q*4+reg.
  // lane l (q<2: cur rows) <-> l^32 (gate rows, same co,px).
  const bool t0 = (t == 0), tL = (t == TT - 1);
  const int co0 = g * 8 + (q & 1) * 4;
  float bc[4], bg[4], th[4];
#pragma unroll
  for (int r = 0; r < 4; ++r) {
    bc[r] = tabs[co0 + r];
    bg[r] = tabs[64 + co0 + r];
    th[r] = tabs[128 + t * 64 + co0 + r];
  }
  const int hh = r0 + hf;
#pragma unroll
  for (int tt = 0; tt < 4; ++tt) {
    const int col = tt * 16 + ln;
    uint fm = 0;
#pragma unroll
    for (int r = 0; r < 4; ++r) {
      // exact-int -> fp32 reconstruction (power-of-2 scales; products exact;
      // small-to-large fmaf chain)
      const float mine = fmaf((float)acc1[tt][r], 0x1p-8f,
                         fmaf((float)acc2[tt][r], 0x1p-15f,
                         fmaf((float)acc3[tt][r], 0x1p-22f,
                              (float)acc4[tt][r] * 0x1p-29f)));
      const float other = __shfl_xor(mine, 32, 64);
      if (q < 2) {
        const int co = co0 + r;
        const size_t idx = ((size_t)((b * 64 + co) * HW + hh)) * HW + col;
        const float cur  = mine + bc[r];
        const float gp   = other + bg[r];
        const float gate = 1.f / (1.f + expf(-gp));
        const float vprev = t0 ? 0.f : vmem[idx];     // t=0: vmem starts at 0
        const float v    = gate * vprev + cur;        // vmem = gate*vmem + current
        const bool fired = (v >= th[r]);              // heaviside(v - thresh_t)
        vmem[idx] = fired ? 0.f : v;                  // hard reset to VRESET=0
        fm |= fired ? (1u << (8 * r)) : 0u;
        float o = (t0 ? 0.f : outp[idx]) + (fired ? 1.f : 0.f);
        if (tL) o *= 0.2f;                            // mean over T=5
        outp[idx] = o;
      }
    }
    if (q < 2)                                        // 4 consecutive co, i8 {0,1}
      *(uint*)(s_dst + ((size_t)((b * HW + hh) * HW + col)) * 64 + co0) = fm;
  }
}

extern "C" void kernel_launch(void* const* d_in, const int* in_sizes, int n_in,
                              void* d_out, int out_size, void* d_ws, size_t ws_size,
                              hipStream_t stream) {
  const float* events = (const float*)d_in[0];
  const float* w_in   = (const float*)d_in[1];
  const float* b_in   = (const float*)d_in[2];
  const float* w_gate = (const float*)d_in[3];
  const float* b_gate = (const float*)d_in[4];
  const float* tdec   = (const float*)d_in[5];
  float* out = (float*)d_out;

  char* base = (char*)d_ws;
  float*       vmem = (float*)base;                    //  8,388,608 B (t0 write-first)
  signed char* sA   = (signed char*)(base + 8388608);  //  2,097,152 B (t0 never read)
  signed char* sB   = (signed char*)(base + 10485760); //  2,097,152 B
  signed char* Wp   = (signed char*)(base + 12582912); //    589,824 B (4 limbs)
  float*       tabs = (float*)(base + 13172736);       //      1,792 B

  hipLaunchKernelGGL(prep_w, dim3(36), dim3(256), 0, stream,
                     w_in, w_gate, b_in, b_gate, tdec, Wp, tabs);

  for (int t = 0; t < TT; ++t) {
    const signed char* ssrc = (t & 1) ? sB : sA;
    signed char*       sdst = (t & 1) ? sA : sB;
    hipLaunchKernelGGL(snn_step, dim3(256), dim3(1024), 0, stream,
                       events, Wp, tabs, vmem, ssrc, sdst, out, t);
  }
}

// Round 14
// 234.225 us; speedup vs baseline: 9.4002x; 1.0096x over previous
//
#include <hip/hip_runtime.h>
#include <cmath>

// DTASNN embedding via i8 QUAD-limb MFMA implicit conv (5 steps + 2 preps).
//
// Inputs binary {0,1} -> exact in i8. Weights as 4 signed-i8 fixed-point limbs:
//   w = 2^-8*L1 + 2^-15*L2 + 2^-22*L3 + 2^-29*L4, residual RMS ~1e-8 (R12: absmax 0.0).
//
// R14 vs R13 (steps ~40us each, dominated by VMEM INSTRUCTION issue: 52k/CU --
// scalar epilogue RMW in [b][co][h][w] + 16 scalar event loads per thread):
//  - vmem + out-accumulator now ch-minor [b][h][w][c] in ws: epilogue = float4
//    R/W (4 contiguous co) -> 20 VMEM/thread (was 68). Final step scatters to
//    d_out's [b][co][h][w] once.
//  - prep_ev reinstated (i8 events): staging = 3 VMEM/thread (was 17).
//  - t=0 reads no state (no memset); t=4 skips vmem/outC/spike stores.
// Per-CU VMEM instrs 52k -> ~13k. Arithmetic identical -> bit-exact.
//
// ws: vmemC 8MB | outC 8MB | sA 2MB | sB 2MB | evb 10.5MB | Wp 576KB | tabs

typedef __attribute__((ext_vector_type(4))) int intx4;

#define HW 64
#define TT 5
#define PLANE 4096
#define CSTR 144                  // U px stride bytes (128 ch + 16 pad): odd 9 quads
#define USIZE (4 * 66 * CSTR)     // 38016 B
#define WPL 147456                // per-limb Wp bytes: 9 tap * 2 ks * 4 q * 128 o * 16

// ---- prep: weight limbs + bias/threshold tables ----
// Wp[limb]: addr = ((tap*2+ks)*4 + q)*2048 + o*16 + j ; o = g*16+i,
// i<8 -> cur row co=g*8+i, i>=8 -> gate row 64+co; c = ks*64 + q*16 + j.
__global__ __launch_bounds__(256) void prep_w(
    const float* __restrict__ w_in, const float* __restrict__ w_gate,
    const float* __restrict__ b_in, const float* __restrict__ b_gate,
    const float* __restrict__ tdec,
    signed char* __restrict__ Wp, float* __restrict__ tabs)
{
  const int idx = blockIdx.x * 256 + threadIdx.x;
  if (idx < 9216) {
    const int o   = idx & 127;
    const int q   = (idx >> 7) & 3;
    const int ks  = (idx >> 9) & 1;
    const int tap = idx >> 10;               // 0..8
    const int g = o >> 4, i = o & 15;
    const int row = (i >> 3) * 64 + g * 8 + (i & 7);
    int p1[4], p2[4], p3[4], p4[4];
#pragma unroll
    for (int wd = 0; wd < 4; ++wd) {
      int v1 = 0, v2 = 0, v3 = 0, v4 = 0;
#pragma unroll
      for (int jb = 0; jb < 4; ++jb) {
        const int j = wd * 4 + jb;
        const int c = ks * 64 + q * 16 + j;
        const float w = (c < 64) ? w_in[(row * 64 + c) * 9 + tap]
                                 : w_gate[(row * 64 + (c - 64)) * 9 + tap];
        float a1 = fminf(fmaxf(rintf(w * 256.f), -127.f), 127.f);
        float r1 = w * 256.f - a1;              // in [-0.5, 0.5]
        float a2 = rintf(r1 * 128.f);
        float r2 = r1 * 128.f - a2;
        float a3 = rintf(r2 * 128.f);
        float r3 = r2 * 128.f - a3;
        float a4 = rintf(r3 * 128.f);
        v1 |= ((int)a1 & 255) << (8 * jb);
        v2 |= ((int)a2 & 255) << (8 * jb);
        v3 |= ((int)a3 & 255) << (8 * jb);
        v4 |= ((int)a4 & 255) << (8 * jb);
      }
      p1[wd] = v1; p2[wd] = v2; p3[wd] = v3; p4[wd] = v4;
    }
    intx4* d = (intx4*)(Wp + (size_t)idx * 16);
    d[0]                          = intx4{p1[0], p1[1], p1[2], p1[3]};
    *(intx4*)((char*)d + WPL)     = intx4{p2[0], p2[1], p2[2], p2[3]};
    *(intx4*)((char*)d + 2 * WPL) = intx4{p3[0], p3[1], p3[2], p3[3]};
    *(intx4*)((char*)d + 3 * WPL) = intx4{p4[0], p4[1], p4[2], p4[3]};
  }
  if (idx < 448) {                           // tabs: bc|bg [128], th [5][64]
    if (idx < 128) tabs[idx] = b_in[idx] + b_gate[idx];
    else {
      const int t = (idx - 128) >> 6, co = (idx - 128) & 63;
      tabs[idx] = powf(tdec[co], (float)t);  // THRESH=1.0
    }
  }
}

// ---- prep: events fp32 [b][tp][c][h][w] -> i8 ch-minor [b][tp][h][w][c] ----
__global__ __launch_bounds__(256) void prep_ev(
    const float* __restrict__ ev, signed char* __restrict__ evb)
{
  const int row  = blockIdx.x * 4 + (threadIdx.x >> 6);  // 0..2559 = (b,tp,h)
  const int w    = threadIdx.x & 63;
  const int b  = row / (TT * HW);
  const int rm = row % (TT * HW);
  const int tp = rm / HW;
  const int h  = rm % HW;
  const float* src = ev + ((size_t)(b * TT + tp) * 64) * PLANE + h * HW + w;
  signed char* dst = evb + ((size_t)((b * TT + tp) * PLANE + h * HW + w)) * 64;
#pragma unroll
  for (int k = 0; k < 8; ++k) {
    unsigned long long pk = 0;
#pragma unroll
    for (int j = 0; j < 8; ++j)
      pk |= (src[(size_t)(k * 8 + j) * PLANE] != 0.f)
              ? (1ull << (8 * j)) : 0ull;
    *(unsigned long long*)(dst + k * 8) = pk;
  }
}

// ---- per-step kernel ----
__global__ __launch_bounds__(1024, 4) void snn_step(
    const signed char* __restrict__ evb,
    const signed char* __restrict__ Wp,
    const float*       __restrict__ tabs,
    float*             __restrict__ vmemC,   // [b][h][w][c] fp32 (ch-minor)
    float*             __restrict__ outC,    // [b][h][w][c] fp32 spike-count acc
    const signed char* __restrict__ s_src,   // [b][h][w][c] i8 {0,1}
    signed char*       __restrict__ s_dst,
    float*             __restrict__ outF,    // d_out [b][co][h][w] fp32
    int t)
{
  __shared__ signed char U[USIZE];  // [row4][col66][c144]: rows r0-1..r0+2, col=img+1

  const int tid = threadIdx.x;               // 0..1023
  const int b   = blockIdx.x >> 5;
  const int r0  = (blockIdx.x & 31) * 2;     // img rows r0, r0+1

  const int lane = tid & 63;
  const int g    = (tid >> 6) & 7;           // o-group 0..7
  const int hf   = tid >> 9;                 // tile-half 0/1 (img row r0+hf)
  const int ln   = lane & 15;                // = A's m = B's n (px col in tile)
  const int q    = lane >> 4;                // k-group 0..3

  // staging: 4 rows x 64 cols x 4 x 32B-chunks (sch<2: events, sch>=2: spikes)
  const int srow = tid >> 8;
  const int scol = (tid >> 2) & 63;
  const int sch  = tid & 3;
  const int sr   = r0 + srow - 1;
  const bool svalid = (sr >= 0) && (sr < HW);

  // issue loads early (results land in regs across the zero-barrier)
  intx4 st0 = intx4{0,0,0,0}, st1 = intx4{0,0,0,0};
  bool sstore = false;
  if (svalid) {
    if (sch < 2) {
      const signed char* gs = evb
          + ((size_t)((b * TT + (TT - 1 - t)) * PLANE + sr * HW + scol)) * 64
          + sch * 32;
      st0 = *(const intx4*)gs; st1 = *(const intx4*)(gs + 16);
      sstore = true;
    } else if (t > 0) {                      // t=0: spikes all-zero, keep U zero
      const signed char* gs = s_src
          + ((size_t)((b * HW + sr) * HW + scol)) * 64 + (sch - 2) * 32;
      st0 = *(const intx4*)gs; st1 = *(const intx4*)(gs + 16);
      sstore = true;
    }
  }

  // ---- zero U (halo col 0/65, out-of-range rows stay 0 = SAME padding) ----
  for (int i = tid; i < USIZE / 16; i += 1024) ((intx4*)U)[i] = intx4{0, 0, 0, 0};
  __syncthreads();
  if (sstore) {
    signed char* du = U + (srow * 66 + scol + 1) * CSTR + sch * 32;
    *(intx4*)du        = st0;
    *(intx4*)(du + 16) = st1;
  }
  __syncthreads();

  // ---- MFMA: acc[limb][tt] (i32, exact), tile (hf*4+tt), K=128 = 2 ks x 64 ----
  intx4 acc1[4], acc2[4], acc3[4], acc4[4];
#pragma unroll
  for (int tt = 0; tt < 4; ++tt) {
    acc1[tt] = intx4{0,0,0,0}; acc2[tt] = intx4{0,0,0,0};
    acc3[tt] = intx4{0,0,0,0}; acc4[tt] = intx4{0,0,0,0};
  }

  const int laneB = ln * CSTR + q * 16;
  const signed char* wlane = Wp + q * 2048 + (g * 16 + ln) * 16;

  for (int tap = 0; tap < 9; ++tap) {
    const int kh = (tap * 11) >> 5;          // tap/3
    const int kw = tap - 3 * kh;
#pragma unroll
    for (int ks = 0; ks < 2; ++ks) {
      const signed char* wp = wlane + (tap * 2 + ks) * 8192;
      const intx4 A1 = *(const intx4*)(wp);
      const intx4 A2 = *(const intx4*)(wp + WPL);
      const intx4 A3 = *(const intx4*)(wp + 2 * WPL);
      const intx4 A4 = *(const intx4*)(wp + 3 * WPL);
      const signed char* ub = U + (hf + kh) * (66 * CSTR) + kw * CSTR + ks * 64 + laneB;
#pragma unroll
      for (int tt = 0; tt < 4; ++tt) {
        const intx4 B = *(const intx4*)(ub + tt * (16 * CSTR));
        acc1[tt] = __builtin_amdgcn_mfma_i32_16x16x64_i8(A1, B, acc1[tt], 0, 0, 0);
        acc2[tt] = __builtin_amdgcn_mfma_i32_16x16x64_i8(A2, B, acc2[tt], 0, 0, 0);
        acc3[tt] = __builtin_amdgcn_mfma_i32_16x16x64_i8(A3, B, acc3[tt], 0, 0, 0);
        acc4[tt] = __builtin_amdgcn_mfma_i32_16x16x64_i8(A4, B, acc4[tt], 0, 0, 0);
      }
    }
  }

  // ---- LIF epilogue, ch-minor float4 state. D: col=lane&15, row(o')=q*4+reg.
  // lane l (q<2: cur rows) <-> l^32 (gate rows, same co,px).
  const bool t0 = (t == 0), tL = (t == TT - 1);
  const int co0 = g * 8 + (q & 1) * 4;
  float bc[4], bg[4], th[4];
#pragma unroll
  for (int r = 0; r < 4; ++r) {
    bc[r] = tabs[co0 + r];
    bg[r] = tabs[64 + co0 + r];
    th[r] = tabs[128 + t * 64 + co0 + r];
  }
  const int hh = r0 + hf;
  const size_t pxbase = ((size_t)(b * HW + hh) * HW) * 64 + co0;  // + col*64
#pragma unroll
  for (int tt = 0; tt < 4; ++tt) {
    const int col = tt * 16 + ln;
    const size_t o = pxbase + (size_t)col * 64;
    float mine[4];
#pragma unroll
    for (int r = 0; r < 4; ++r)
      mine[r] = fmaf((float)acc1[tt][r], 0x1p-8f,
                fmaf((float)acc2[tt][r], 0x1p-15f,
                fmaf((float)acc3[tt][r], 0x1p-22f,
                     (float)acc4[tt][r] * 0x1p-29f)));
    float other[4];
#pragma unroll
    for (int r = 0; r < 4; ++r) other[r] = __shfl_xor(mine[r], 32, 64);
    if (q < 2) {
      float4 vm4 = t0 ? float4{0.f,0.f,0.f,0.f} : *(const float4*)&vmemC[o];
      float4 oc4 = t0 ? float4{0.f,0.f,0.f,0.f} : *(const float4*)&outC[o];
      uint fm = 0;
#pragma unroll
      for (int r = 0; r < 4; ++r) {
        const float cur  = mine[r] + bc[r];
        const float gp   = other[r] + bg[r];
        const float gate = 1.f / (1.f + expf(-gp));
        const float v    = gate * (&vm4.x)[r] + cur;  // vmem = gate*vmem + current
        const bool fired = (v >= th[r]);              // heaviside(v - thresh_t)
        (&vm4.x)[r] = fired ? 0.f : v;                // hard reset to VRESET=0
        (&oc4.x)[r] += fired ? 1.f : 0.f;
        fm |= fired ? (1u << (8 * r)) : 0u;
      }
      if (!tL) {
        *(float4*)&vmemC[o] = vm4;
        *(float4*)&outC[o]  = oc4;
        *(uint*)&s_dst[o]   = fm;                     // same ch-minor index
      } else {
        // final: mean over T=5, scatter to d_out's [b][co][h][w]
#pragma unroll
        for (int r = 0; r < 4; ++r)
          outF[((size_t)((b * 64 + co0 + r) * HW + hh)) * HW + col]
              = (&oc4.x)[r] * 0.2f;
      }
    }
  }
}

extern "C" void kernel_launch(void* const* d_in, const int* in_sizes, int n_in,
                              void* d_out, int out_size, void* d_ws, size_t ws_size,
                              hipStream_t stream) {
  const float* events = (const float*)d_in[0];
  const float* w_in   = (const float*)d_in[1];
  const float* b_in   = (const float*)d_in[2];
  const float* w_gate = (const float*)d_in[3];
  const float* b_gate = (const float*)d_in[4];
  const float* tdec   = (const float*)d_in[5];
  float* out = (float*)d_out;

  char* base = (char*)d_ws;
  float*       vmemC = (float*)base;                    //  8,388,608 B (t0 write-first)
  float*       outC  = (float*)(base + 8388608);        //  8,388,608 B (t0 write-first)
  signed char* sA    = (signed char*)(base + 16777216); //  2,097,152 B (t0 never read)
  signed char* sB    = (signed char*)(base + 18874368); //  2,097,152 B
  signed char* evb   = (signed char*)(base + 20971520); // 10,485,760 B
  signed char* Wp    = (signed char*)(base + 31457280); //    589,824 B (4 limbs)
  float*       tabs  = (float*)(base + 32047104);       //      1,792 B

  hipLaunchKernelGGL(prep_w,  dim3(36),  dim3(256), 0, stream,
                     w_in, w_gate, b_in, b_gate, tdec, Wp, tabs);
  hipLaunchKernelGGL(prep_ev, dim3(640), dim3(256), 0, stream, events, evb);

  for (int t = 0; t < TT; ++t) {
    const signed char* ssrc = (t & 1) ? sB : sA;
    signed char*       sdst = (t & 1) ? sA : sB;
    hipLaunchKernelGGL(snn_step, dim3(256), dim3(1024), 0, stream,
                       evb, Wp, tabs, vmemC, outC, ssrc, sdst, out, t);
  }
}